// Round 1
// baseline (648.391 us; speedup 1.0000x reference)
//
#include <hip/hip_runtime.h>

#define Bb 8
#define Ss 2048
#define Ee 1024
#define Dd 1024

typedef __attribute__((ext_vector_type(8))) __bf16 bf16x8;
typedef __attribute__((ext_vector_type(4))) float f32x4;
typedef unsigned short u16;

__device__ __forceinline__ u16 f2bf(float x) {
  unsigned u = __float_as_uint(x);
  return (u16)((u + 0x7fffu + ((u >> 16) & 1u)) >> 16);
}
__device__ __forceinline__ float bf2f(u16 h) {
  return __uint_as_float(((unsigned)h) << 16);
}

__device__ __forceinline__ void gload16(const void* g, void* l) {
  __builtin_amdgcn_global_load_lds(
      (__attribute__((address_space(1))) void*)const_cast<void*>(g),
      (__attribute__((address_space(3))) void*)l, 16, 0, 0);
}

// ---------------- fp32 -> bf16 hi/lo split (vectorized x4) ----------------
__global__ __launch_bounds__(256) void k_split4(const float* __restrict__ in,
                                                u16* __restrict__ hi,
                                                u16* __restrict__ lo,
                                                long long n4) {
  long long i = (long long)blockIdx.x * 256 + threadIdx.x;
  if (i >= n4) return;
  float4 v = ((const float4*)in)[i];
  float xs[4] = {v.x, v.y, v.z, v.w};
  u16 hh[4], ll[4];
#pragma unroll
  for (int j = 0; j < 4; ++j) {
    hh[j] = f2bf(xs[j]);
    ll[j] = f2bf(xs[j] - bf2f(hh[j]));
  }
  ushort4 h, l;
  h.x = hh[0]; h.y = hh[1]; h.z = hh[2]; h.w = hh[3];
  l.x = ll[0]; l.y = ll[1]; l.z = ll[2]; l.w = ll[3];
  ((ushort4*)hi)[i] = h;
  ((ushort4*)lo)[i] = l;
}

// ---------------- W [E,D] fp32 -> W^T [D,E] bf16 hi(/lo) ----------------
__global__ __launch_bounds__(256) void k_wt_split(const float* __restrict__ W,
                                                  u16* __restrict__ hi,
                                                  u16* __restrict__ lo) {
  __shared__ float t[32][33];
  const int tx = threadIdx.x & 31;
  const int ty = threadIdx.x >> 5;  // 0..7
  const int e0 = blockIdx.y * 32, d0 = blockIdx.x * 32;
#pragma unroll
  for (int r = ty; r < 32; r += 8)
    t[r][tx] = W[(long long)(e0 + r) * Dd + d0 + tx];
  __syncthreads();
#pragma unroll
  for (int r = ty; r < 32; r += 8) {
    float x = t[tx][r];  // = W[e0+tx][d0+r]
    long long o = (long long)(d0 + r) * Ee + e0 + tx;
    u16 h = f2bf(x);
    hi[o] = h;
    if (lo) lo[o] = f2bf(x - bf2f(h));
  }
}

// ---------------- 128x128-tile BT-layout MFMA GEMM ----------------
// C[M,N] = A[M,K] * B^T where B given as [N,K].  NPASS=3: split-precision
// (A,B given as hi/lo bf16 pairs, acc += Ah*Bh + Ah*Bl + Al*Bh).
// EPI: 0 = fp32 store to Cf; 1 = split hi/lo bf16 store; 2 = bf16 store.
// CSKIP: skip tiles with bx > by (causal).  TRIK: truncate K at (by+1)*128.
template <int NPASS, int EPI, bool CSKIP, bool TRIK>
__global__ __launch_bounds__(256) void k_gemm_bt(
    const u16* __restrict__ Ah, const u16* __restrict__ Al,
    const u16* __restrict__ Bh, const u16* __restrict__ Bl,
    float* __restrict__ Cf, u16* __restrict__ Ch, u16* __restrict__ Cl,
    int M, int N, int K, long long strA, long long strB, long long strC) {
  const int bx = blockIdx.x, by = blockIdx.y, bz = blockIdx.z;
  if (CSKIP && bx > by) return;

  const int tid = threadIdx.x;
  const int lane = tid & 63;
  const int w = tid >> 6;
  const int wr = w >> 1, wc = w & 1;

  const u16* pAh = Ah + (long long)bz * strA;
  const u16* pBh = Bh + (long long)bz * strB;
  const u16* pAl = (NPASS == 3) ? (Al + (long long)bz * strA) : nullptr;
  const u16* pBl = (NPASS == 3) ? (Bl + (long long)bz * strB) : nullptr;

  constexpr int NT = (NPASS == 3) ? 4 : 2;
  __shared__ __align__(16) u16 lds[NT * 128 * 32];
  char* ldsc = (char*)lds;

  // staging map: thread t covers 8 bf16 at tile (row=t/4 [+64], col=(t&3)*8)
  const int srow = tid >> 2;
  const int scol = (tid & 3) * 8;
  const long long arow = (long long)by * 128 + srow;
  const long long brow = (long long)bx * 128 + srow;

  int ktEnd = K / 32;
  if (TRIK) {
    int lim = ((by + 1) * 128) / 32;
    if (lim < ktEnd) ktEnd = lim;
  }

  f32x4 acc[4][4];
#pragma unroll
  for (int i = 0; i < 4; ++i)
#pragma unroll
    for (int j = 0; j < 4; ++j) acc[i][j] = f32x4{0.f, 0.f, 0.f, 0.f};

  for (int kt = 0; kt < ktEnd; ++kt) {
    const int k0 = kt * 32 + scol;
    __syncthreads();  // previous iter's LDS reads done before overwrite
    gload16(pAh + arow * K + k0, ldsc + 0 * 4096 + w * 1024);
    gload16(pAh + (arow + 64) * K + k0, ldsc + 1 * 4096 + w * 1024);
    gload16(pBh + brow * K + k0, ldsc + 8192 + 0 * 4096 + w * 1024);
    gload16(pBh + (brow + 64) * K + k0, ldsc + 8192 + 1 * 4096 + w * 1024);
    if constexpr (NPASS == 3) {
      gload16(pAl + arow * K + k0, ldsc + 16384 + 0 * 4096 + w * 1024);
      gload16(pAl + (arow + 64) * K + k0, ldsc + 16384 + 1 * 4096 + w * 1024);
      gload16(pBl + brow * K + k0, ldsc + 24576 + 0 * 4096 + w * 1024);
      gload16(pBl + (brow + 64) * K + k0, ldsc + 24576 + 1 * 4096 + w * 1024);
    }
    __syncthreads();  // compiler drains vmcnt before s_barrier -> staging done

    const int kk = (lane >> 4) * 8;
    const int ar = wr * 64 + (lane & 15);
    const int br = wc * 64 + (lane & 15);
    bf16x8 avh[4], bvh[4];
#pragma unroll
    for (int m = 0; m < 4; ++m)
      avh[m] = *(const bf16x8*)(lds + (ar + m * 16) * 32 + kk);
#pragma unroll
    for (int n = 0; n < 4; ++n)
      bvh[n] = *(const bf16x8*)(lds + 128 * 32 + (br + n * 16) * 32 + kk);
    if constexpr (NPASS == 3) {
      bf16x8 avl[4], bvl[4];
#pragma unroll
      for (int m = 0; m < 4; ++m)
        avl[m] = *(const bf16x8*)(lds + 2 * 128 * 32 + (ar + m * 16) * 32 + kk);
#pragma unroll
      for (int n = 0; n < 4; ++n)
        bvl[n] = *(const bf16x8*)(lds + 3 * 128 * 32 + (br + n * 16) * 32 + kk);
#pragma unroll
      for (int m = 0; m < 4; ++m)
#pragma unroll
        for (int n = 0; n < 4; ++n) {
          acc[m][n] = __builtin_amdgcn_mfma_f32_16x16x32_bf16(avh[m], bvh[n], acc[m][n], 0, 0, 0);
          acc[m][n] = __builtin_amdgcn_mfma_f32_16x16x32_bf16(avh[m], bvl[n], acc[m][n], 0, 0, 0);
          acc[m][n] = __builtin_amdgcn_mfma_f32_16x16x32_bf16(avl[m], bvh[n], acc[m][n], 0, 0, 0);
        }
    } else {
#pragma unroll
      for (int m = 0; m < 4; ++m)
#pragma unroll
        for (int n = 0; n < 4; ++n)
          acc[m][n] = __builtin_amdgcn_mfma_f32_16x16x32_bf16(avh[m], bvh[n], acc[m][n], 0, 0, 0);
    }
  }

  // epilogue: C/D map col=lane&15, row=(lane>>4)*4+reg  [verified m89/m91]
  const int cr = wr * 64 + ((lane >> 4) << 2);
  const int cc = wc * 64 + (lane & 15);
  const long long rb = (long long)by * 128 + cr;
  const long long cb = (long long)bx * 128 + cc;
#pragma unroll
  for (int m = 0; m < 4; ++m)
#pragma unroll
    for (int n = 0; n < 4; ++n)
#pragma unroll
      for (int r = 0; r < 4; ++r) {
        const long long idx =
            (long long)bz * strC + (rb + m * 16 + r) * (long long)N + (cb + n * 16);
        const float v = acc[m][n][r];
        if constexpr (EPI == 0) {
          Cf[idx] = v;
        } else if constexpr (EPI == 1) {
          u16 h = f2bf(v);
          Ch[idx] = h;
          Cl[idx] = f2bf(v - bf2f(h));
        } else {
          Ch[idx] = f2bf(v);
        }
      }
}

// ---------------- causal+pad masked row softmax (in-place) ----------------
__global__ __launch_bounds__(256) void k_softmax(float* __restrict__ attn,
                                                 u16* __restrict__ attn_bf,
                                                 const int* __restrict__ mask,
                                                 float inv_scale) {
  const int q = blockIdx.x;
  const int b = blockIdx.y;
  const int tid = threadIdx.x;
  float* row = attn + ((long long)b * Ss + q) * Ss;
  u16* rowb = attn_bf + ((long long)b * Ss + q) * Ss;
  const int* mrow = mask + b * Ss;

  float x[8];
  float m = -3.0e38f;
#pragma unroll
  for (int j = 0; j < 8; ++j) {
    const int k = tid + j * 256;
    const float e = row[k];
    const bool ok = (k <= q) && (mrow[k] != 0);
    // mirror reference: masked -> NEG, then /scale
    const float v = (ok ? e : -1e20f) * inv_scale;
    x[j] = v;
    m = fmaxf(m, v);
  }
#pragma unroll
  for (int o = 32; o > 0; o >>= 1) m = fmaxf(m, __shfl_xor(m, o));
  __shared__ float redm[4], reds[4];
  const int w = tid >> 6;
  if ((tid & 63) == 0) redm[w] = m;
  __syncthreads();
  m = fmaxf(fmaxf(redm[0], redm[1]), fmaxf(redm[2], redm[3]));
  float s = 0.f;
#pragma unroll
  for (int j = 0; j < 8; ++j) {
    x[j] = __expf(x[j] - m);
    s += x[j];
  }
#pragma unroll
  for (int o = 32; o > 0; o >>= 1) s += __shfl_xor(s, o);
  if ((tid & 63) == 0) reds[w] = s;
  __syncthreads();
  s = reds[0] + reds[1] + reds[2] + reds[3];
  const float inv = 1.0f / s;
#pragma unroll
  for (int j = 0; j < 8; ++j) {
    const int k = tid + j * 256;
    const float a = x[j] * inv;
    row[k] = a;
    rowb[k] = f2bf(a);
  }
}

extern "C" void kernel_launch(void* const* d_in, const int* in_sizes, int n_in,
                              void* d_out, int out_size, void* d_ws, size_t ws_size,
                              hipStream_t stream) {
  const float* emb = (const float*)d_in[0];
  const int* mask = (const int*)d_in[1];
  const float* Wq = (const float*)d_in[2];
  const float* Wk = (const float*)d_in[3];
  const float* Wv = (const float*)d_in[4];

  float* out = (float*)d_out;                         // [8,2048,1024] fp32
  float* attn = out + (long long)Bb * Ss * Dd;        // [8,2048,2048] fp32 (also energy scratch)

  // workspace carve (~245.4 MB total)
  char* p = (char*)d_ws;
  u16* emb_hi = (u16*)p;                        // 33,554,432 B
  u16* emb_lo = emb_hi + (long long)Bb * Ss * Ee;
  u16* attn_bf = emb_hi;                        // alias: emb dead before softmax
  u16* q_hi = (u16*)(p + 67108864LL);
  u16* q_lo = q_hi + 16777216LL;
  u16* k_hi = q_lo + 16777216LL;
  u16* k_lo = k_hi + 16777216LL;
  u16* v_t = k_lo + 16777216LL;                 // [b][D][S] bf16
  u16* Wq_hi = v_t + 16777216LL;
  u16* Wq_lo = Wq_hi + 1048576LL;
  u16* Wk_hi = Wq_lo + 1048576LL;
  u16* Wk_lo = Wk_hi + 1048576LL;
  u16* Wv_hi = Wk_lo + 1048576LL;

  const float inv_scale = 1.0f / (32.0f + 1.1920929e-07f);  // 1/(sqrt(1024)+eps)

  k_split4<<<16384, 256, 0, stream>>>(emb, emb_hi, emb_lo, (long long)Bb * Ss * Ee / 4);
  k_wt_split<<<dim3(32, 32), 256, 0, stream>>>(Wq, Wq_hi, Wq_lo);
  k_wt_split<<<dim3(32, 32), 256, 0, stream>>>(Wk, Wk_hi, Wk_lo);
  k_wt_split<<<dim3(32, 32), 256, 0, stream>>>(Wv, Wv_hi, nullptr);

  // q = emb @ Wq  (split-precision, split-bf16 output)  M=16384,N=1024,K=1024
  k_gemm_bt<3, 1, false, false><<<dim3(8, 128, 1), 256, 0, stream>>>(
      emb_hi, emb_lo, Wq_hi, Wq_lo, nullptr, q_hi, q_lo, 16384, 1024, 1024, 0, 0, 0);
  k_gemm_bt<3, 1, false, false><<<dim3(8, 128, 1), 256, 0, stream>>>(
      emb_hi, emb_lo, Wk_hi, Wk_lo, nullptr, k_hi, k_lo, 16384, 1024, 1024, 0, 0, 0);
  // v^T per batch: [D,S] = Wv^T[D,E] @ emb_b[S,E]^T-layout (single-pass bf16)
  k_gemm_bt<1, 2, false, false><<<dim3(16, 8, 8), 256, 0, stream>>>(
      Wv_hi, nullptr, emb_hi, nullptr, nullptr, v_t, nullptr,
      1024, 2048, 1024, 0, (long long)Ss * Ee, (long long)Dd * Ss);
  // energy per batch: [S,S] = q_b @ k_b^T (split-precision, causal tile-skip)
  k_gemm_bt<3, 0, true, false><<<dim3(16, 16, 8), 256, 0, stream>>>(
      q_hi, q_lo, k_hi, k_lo, attn, nullptr, nullptr,
      2048, 2048, 1024, (long long)Ss * Dd, (long long)Ss * Dd, (long long)Ss * Ss);
  // softmax rows in-place + bf16 copy
  k_softmax<<<dim3(Ss, Bb), 256, 0, stream>>>(attn, attn_bf, mask, inv_scale);
  // out per batch: [S,D] = attn_bf @ v (v_t is the BT operand), K truncated causally
  k_gemm_bt<1, 0, false, true><<<dim3(8, 16, 8), 256, 0, stream>>>(
      attn_bf, nullptr, v_t, nullptr, out, nullptr, nullptr,
      2048, 1024, 2048, (long long)Ss * Ss, (long long)Dd * Ss, (long long)Ss * Dd);
}

// Round 2
// 600.967 us; speedup vs baseline: 1.0789x; 1.0789x over previous
//
#include <hip/hip_runtime.h>

#define Bb 8
#define Ss 2048
#define Ee 1024
#define Dd 1024

typedef __attribute__((ext_vector_type(8))) __bf16 bf16x8;
typedef __attribute__((ext_vector_type(4))) float f32x4;
typedef unsigned short u16;

__device__ __forceinline__ u16 f2bf(float x) {
  unsigned u = __float_as_uint(x);
  return (u16)((u + 0x7fffu + ((u >> 16) & 1u)) >> 16);
}
__device__ __forceinline__ float bf2f(u16 h) {
  return __uint_as_float(((unsigned)h) << 16);
}

__device__ __forceinline__ void gload16(const void* g, void* l) {
  __builtin_amdgcn_global_load_lds(
      (__attribute__((address_space(1))) void*)const_cast<void*>(g),
      (__attribute__((address_space(3))) void*)l, 16, 0, 0);
}

#define MFMA_BF16 __builtin_amdgcn_mfma_f32_16x16x32_bf16

// ---------------- fp32 -> bf16 hi/lo split (vectorized x4) ----------------
__global__ __launch_bounds__(256) void k_split4(const float* __restrict__ in,
                                                u16* __restrict__ hi,
                                                u16* __restrict__ lo,
                                                long long n4) {
  long long i = (long long)blockIdx.x * 256 + threadIdx.x;
  if (i >= n4) return;
  float4 v = ((const float4*)in)[i];
  float xs[4] = {v.x, v.y, v.z, v.w};
  u16 hh[4], ll[4];
#pragma unroll
  for (int j = 0; j < 4; ++j) {
    hh[j] = f2bf(xs[j]);
    ll[j] = f2bf(xs[j] - bf2f(hh[j]));
  }
  ushort4 h, l;
  h.x = hh[0]; h.y = hh[1]; h.z = hh[2]; h.w = hh[3];
  l.x = ll[0]; l.y = ll[1]; l.z = ll[2]; l.w = ll[3];
  ((ushort4*)hi)[i] = h;
  ((ushort4*)lo)[i] = l;
}

// ---------------- W [E,D] fp32 -> W^T [D,E] bf16 hi(/lo) ----------------
__global__ __launch_bounds__(256) void k_wt_split(const float* __restrict__ W,
                                                  u16* __restrict__ hi,
                                                  u16* __restrict__ lo) {
  __shared__ float t[32][33];
  const int tx = threadIdx.x & 31;
  const int ty = threadIdx.x >> 5;  // 0..7
  const int e0 = blockIdx.y * 32, d0 = blockIdx.x * 32;
#pragma unroll
  for (int r = ty; r < 32; r += 8)
    t[r][tx] = W[(long long)(e0 + r) * Dd + d0 + tx];
  __syncthreads();
#pragma unroll
  for (int r = ty; r < 32; r += 8) {
    float x = t[tx][r];  // = W[e0+tx][d0+r]
    long long o = (long long)(d0 + r) * Ee + e0 + tx;
    u16 h = f2bf(x);
    hi[o] = h;
    if (lo) lo[o] = f2bf(x - bf2f(h));
  }
}

// ============ 8-phase 256x256 split-precision (NPASS=3) BT GEMM ============
// C[M,N] = (Ah+Al)(Bh+Bl)^T (drop Al*Bl).  A:[M,K] hi/lo, B:[N,K] hi/lo.
// 8 waves (2M x 4N), per-wave 128x64 out, BK=32, double-buffered LDS 128KiB.
// Per K-tile: 4 phases x {ds_read subtile, 2x global_load_lds, barrier,
// setprio(1) 24 MFMA setprio(0), barrier}; counted vmcnt(2) at phase 0.
// LDS chunk-XOR swizzle (chunk ^= (row>>1)&3) on BOTH gload-source and read.
// EPI: 0 = fp32 store, 1 = split hi/lo bf16 store.  CSKIP: skip bx>by tiles.
template <int EPI, bool CSKIP>
__global__ __launch_bounds__(512, 2) void k_gemm256(
    const u16* __restrict__ Ah, const u16* __restrict__ Al,
    const u16* __restrict__ Bh, const u16* __restrict__ Bl,
    float* __restrict__ Cf, u16* __restrict__ Ch, u16* __restrict__ Cl,
    int N, int K, long long strA, long long strB, long long strC) {
  const int bx = blockIdx.x, by = blockIdx.y, bz = blockIdx.z;
  if (CSKIP && bx > by) return;

  // lds[buf][mat][16KB tile]; mat: 0=Ah 1=Al 2=Bh 3=Bl.  Tile = 256 rows x
  // 32 bf16 (64B rows, 4x16B chunks, chunk XOR-swizzled by (row>>1)&3).
  __shared__ __align__(16) u16 lds[2][4][8192];

  const int tid = threadIdx.x;
  const int lane = tid & 63;
  const int w = tid >> 6;          // 0..7
  const int wr = w >> 2;           // 0..1  (M half)
  const int wc = w & 3;            // 0..3  (N quarter)

  const u16* srcBase[4] = {Ah + (long long)bz * strA, Al + (long long)bz * strA,
                           Bh + (long long)bz * strB, Bl + (long long)bz * strB};
  const long long row0[2] = {(long long)by * 256, (long long)bx * 256};

  // staging map: thread covers dest byte (half*8192 + tid*16) of a tile ->
  // row rL = half*128 + (tid>>2), chunk j = tid&3; swizzled source chunk
  // jx = j ^ ((row>>1)&3) = (tid&3) ^ ((tid>>3)&3)   (half*128 drops out).
  const int rL = tid >> 2;
  const int colOff = ((tid & 3) ^ ((tid >> 3) & 3)) * 8;

  // frag-read offset: row = R + (lane&15), chunk = lane>>4; swizzled byte =
  // row*64 + (chunk ^ ((row>>1)&3))*16; R%16==0 -> xor sel = (lane>>1)&3.
  const int rdOff = (lane & 15) * 64 + ((((lane >> 4) & 3) ^ ((lane >> 1) & 3)) << 4);

  const int AR = wr * 128;
  const int BR = wc * 64;
  const int nt = K / 32;

#define STAGE2(buf, kt, p)                                                      \
  {                                                                             \
    _Pragma("unroll") for (int i = 0; i < 2; ++i) {                             \
      const int b = 2 * (p) + i;                                                \
      const int mat = b >> 1, half = b & 1;                                     \
      const long long grow = row0[mat >> 1] + half * 128 + rL;                  \
      gload16(srcBase[mat] + grow * K + (kt)*32 + colOff,                       \
              (char*)&lds[buf][mat][0] + half * 8192 + w * 1024);               \
    }                                                                           \
  }

#define LDFRAG(buf, mat, R) \
  (*(const bf16x8*)((const char*)&lds[buf][mat][0] + (R)*64 + rdOff))

  f32x4 acc[8][4];
#pragma unroll
  for (int m = 0; m < 8; ++m)
#pragma unroll
    for (int n = 0; n < 4; ++n) acc[m][n] = f32x4{0.f, 0.f, 0.f, 0.f};

  bf16x8 a_h[4], a_l[4], b_h[4], b_l[4];

  // prologue: stage tile 0 fully (8 loads)
#pragma unroll
  for (int p = 0; p < 4; ++p) STAGE2(0, 0, p);

  for (int kt = 0; kt < nt; ++kt) {
    const int cur = kt & 1;
    const bool more = (kt + 1 < nt);

    // ---- phase 0: vmcnt-gated buffer swap; A m0-3 + B n0-1; MFMA 24 ----
    if (more) {
      STAGE2(cur ^ 1, kt + 1, 0);
      asm volatile("s_waitcnt vmcnt(2)" ::: "memory");
    } else {
      asm volatile("s_waitcnt vmcnt(0)" ::: "memory");
    }
    __builtin_amdgcn_s_barrier();
    __builtin_amdgcn_sched_barrier(0);
#pragma unroll
    for (int m = 0; m < 4; ++m) {
      a_h[m] = LDFRAG(cur, 0, AR + m * 16);
      a_l[m] = LDFRAG(cur, 1, AR + m * 16);
    }
#pragma unroll
    for (int n = 0; n < 2; ++n) {
      b_h[n] = LDFRAG(cur, 2, BR + n * 16);
      b_l[n] = LDFRAG(cur, 3, BR + n * 16);
    }
    __builtin_amdgcn_s_setprio(1);
#pragma unroll
    for (int m = 0; m < 4; ++m)
#pragma unroll
      for (int n = 0; n < 2; ++n) {
        acc[m][n] = MFMA_BF16(a_h[m], b_l[n], acc[m][n], 0, 0, 0);
        acc[m][n] = MFMA_BF16(a_l[m], b_h[n], acc[m][n], 0, 0, 0);
        acc[m][n] = MFMA_BF16(a_h[m], b_h[n], acc[m][n], 0, 0, 0);
      }
    __builtin_amdgcn_s_setprio(0);
    __builtin_amdgcn_s_barrier();

    // ---- phase 1: B n2-3; MFMA m0-3 x n2-3 ----
#pragma unroll
    for (int n = 2; n < 4; ++n) {
      b_h[n] = LDFRAG(cur, 2, BR + n * 16);
      b_l[n] = LDFRAG(cur, 3, BR + n * 16);
    }
    if (more) STAGE2(cur ^ 1, kt + 1, 1);
    __builtin_amdgcn_s_barrier();
    __builtin_amdgcn_s_setprio(1);
#pragma unroll
    for (int m = 0; m < 4; ++m)
#pragma unroll
      for (int n = 2; n < 4; ++n) {
        acc[m][n] = MFMA_BF16(a_h[m], b_l[n], acc[m][n], 0, 0, 0);
        acc[m][n] = MFMA_BF16(a_l[m], b_h[n], acc[m][n], 0, 0, 0);
        acc[m][n] = MFMA_BF16(a_h[m], b_h[n], acc[m][n], 0, 0, 0);
      }
    __builtin_amdgcn_s_setprio(0);
    __builtin_amdgcn_s_barrier();

    // ---- phase 2: A m4-7 (reuse regs); MFMA m4-7 x n0-1 ----
#pragma unroll
    for (int m = 0; m < 4; ++m) {
      a_h[m] = LDFRAG(cur, 0, AR + 64 + m * 16);
      a_l[m] = LDFRAG(cur, 1, AR + 64 + m * 16);
    }
    if (more) STAGE2(cur ^ 1, kt + 1, 2);
    __builtin_amdgcn_s_barrier();
    __builtin_amdgcn_s_setprio(1);
#pragma unroll
    for (int m = 0; m < 4; ++m)
#pragma unroll
      for (int n = 0; n < 2; ++n) {
        acc[4 + m][n] = MFMA_BF16(a_h[m], b_l[n], acc[4 + m][n], 0, 0, 0);
        acc[4 + m][n] = MFMA_BF16(a_l[m], b_h[n], acc[4 + m][n], 0, 0, 0);
        acc[4 + m][n] = MFMA_BF16(a_h[m], b_h[n], acc[4 + m][n], 0, 0, 0);
      }
    __builtin_amdgcn_s_setprio(0);
    __builtin_amdgcn_s_barrier();

    // ---- phase 3: no reads; MFMA m4-7 x n2-3 ----
    if (more) STAGE2(cur ^ 1, kt + 1, 3);
    __builtin_amdgcn_s_barrier();
    __builtin_amdgcn_s_setprio(1);
#pragma unroll
    for (int m = 0; m < 4; ++m)
#pragma unroll
      for (int n = 2; n < 4; ++n) {
        acc[4 + m][n] = MFMA_BF16(a_h[m], b_l[n], acc[4 + m][n], 0, 0, 0);
        acc[4 + m][n] = MFMA_BF16(a_l[m], b_h[n], acc[4 + m][n], 0, 0, 0);
        acc[4 + m][n] = MFMA_BF16(a_h[m], b_h[n], acc[4 + m][n], 0, 0, 0);
      }
    __builtin_amdgcn_s_setprio(0);
    __builtin_amdgcn_s_barrier();
  }

  // epilogue: C/D map col=lane&15, row=(lane>>4)*4+reg
  const int cr = (lane >> 4) << 2;
  const int cc = lane & 15;
#pragma unroll
  for (int m = 0; m < 8; ++m)
#pragma unroll
    for (int n = 0; n < 4; ++n)
#pragma unroll
      for (int r = 0; r < 4; ++r) {
        const long long row = (long long)by * 256 + wr * 128 + m * 16 + cr + r;
        const long long col = (long long)bx * 256 + wc * 64 + n * 16 + cc;
        const long long idx = (long long)bz * strC + row * N + col;
        const float v = acc[m][n][r];
        if constexpr (EPI == 0) {
          Cf[idx] = v;
        } else {
          u16 h = f2bf(v);
          Ch[idx] = h;
          Cl[idx] = f2bf(v - bf2f(h));
        }
      }
#undef STAGE2
#undef LDFRAG
}

// ---------------- 128x128-tile BT-layout MFMA GEMM (NPASS=1 only now) ------
// EPI: 0 = fp32 store; 2 = bf16 store.  TRIK: truncate K at (by+1)*128.
template <int EPI, bool TRIK>
__global__ __launch_bounds__(256) void k_gemm_bt(
    const u16* __restrict__ Ah, const u16* __restrict__ Bh,
    float* __restrict__ Cf, u16* __restrict__ Ch,
    int M, int N, int K, long long strA, long long strB, long long strC) {
  const int bx = blockIdx.x, by = blockIdx.y, bz = blockIdx.z;

  const int tid = threadIdx.x;
  const int lane = tid & 63;
  const int w = tid >> 6;
  const int wr = w >> 1, wc = w & 1;

  const u16* pAh = Ah + (long long)bz * strA;
  const u16* pBh = Bh + (long long)bz * strB;

  __shared__ __align__(16) u16 lds[2 * 128 * 32];
  char* ldsc = (char*)lds;

  const int srow = tid >> 2;
  const int scol = (tid & 3) * 8;
  const long long arow = (long long)by * 128 + srow;
  const long long brow = (long long)bx * 128 + srow;

  int ktEnd = K / 32;
  if (TRIK) {
    int lim = ((by + 1) * 128) / 32;
    if (lim < ktEnd) ktEnd = lim;
  }

  f32x4 acc[4][4];
#pragma unroll
  for (int i = 0; i < 4; ++i)
#pragma unroll
    for (int j = 0; j < 4; ++j) acc[i][j] = f32x4{0.f, 0.f, 0.f, 0.f};

  for (int kt = 0; kt < ktEnd; ++kt) {
    const int k0 = kt * 32 + scol;
    __syncthreads();
    gload16(pAh + arow * K + k0, ldsc + 0 * 4096 + w * 1024);
    gload16(pAh + (arow + 64) * K + k0, ldsc + 1 * 4096 + w * 1024);
    gload16(pBh + brow * K + k0, ldsc + 8192 + 0 * 4096 + w * 1024);
    gload16(pBh + (brow + 64) * K + k0, ldsc + 8192 + 1 * 4096 + w * 1024);
    __syncthreads();

    const int kk = (lane >> 4) * 8;
    const int ar = wr * 64 + (lane & 15);
    const int br = wc * 64 + (lane & 15);
    bf16x8 avh[4], bvh[4];
#pragma unroll
    for (int m = 0; m < 4; ++m)
      avh[m] = *(const bf16x8*)(lds + (ar + m * 16) * 32 + kk);
#pragma unroll
    for (int n = 0; n < 4; ++n)
      bvh[n] = *(const bf16x8*)(lds + 128 * 32 + (br + n * 16) * 32 + kk);
#pragma unroll
    for (int m = 0; m < 4; ++m)
#pragma unroll
      for (int n = 0; n < 4; ++n)
        acc[m][n] = MFMA_BF16(avh[m], bvh[n], acc[m][n], 0, 0, 0);
  }

  const int cr = wr * 64 + ((lane >> 4) << 2);
  const int cc = wc * 64 + (lane & 15);
  const long long rb = (long long)by * 128 + cr;
  const long long cb = (long long)bx * 128 + cc;
#pragma unroll
  for (int m = 0; m < 4; ++m)
#pragma unroll
    for (int n = 0; n < 4; ++n)
#pragma unroll
      for (int r = 0; r < 4; ++r) {
        const long long idx =
            (long long)bz * strC + (rb + m * 16 + r) * (long long)N + (cb + n * 16);
        const float v = acc[m][n][r];
        if constexpr (EPI == 0) Cf[idx] = v;
        else Ch[idx] = f2bf(v);
      }
}

// ---------------- causal+pad masked row softmax (in-place) ----------------
__global__ __launch_bounds__(256) void k_softmax(float* __restrict__ attn,
                                                 u16* __restrict__ attn_bf,
                                                 const int* __restrict__ mask,
                                                 float inv_scale) {
  const int q = blockIdx.x;
  const int b = blockIdx.y;
  const int tid = threadIdx.x;
  float* row = attn + ((long long)b * Ss + q) * Ss;
  u16* rowb = attn_bf + ((long long)b * Ss + q) * Ss;
  const int* mrow = mask + b * Ss;

  float x[8];
  float m = -3.0e38f;
#pragma unroll
  for (int j = 0; j < 8; ++j) {
    const int k = tid + j * 256;
    const float e = row[k];
    const bool ok = (k <= q) && (mrow[k] != 0);
    const float v = (ok ? e : -1e20f) * inv_scale;
    x[j] = v;
    m = fmaxf(m, v);
  }
#pragma unroll
  for (int o = 32; o > 0; o >>= 1) m = fmaxf(m, __shfl_xor(m, o));
  __shared__ float redm[4], reds[4];
  const int w = tid >> 6;
  if ((tid & 63) == 0) redm[w] = m;
  __syncthreads();
  m = fmaxf(fmaxf(redm[0], redm[1]), fmaxf(redm[2], redm[3]));
  float s = 0.f;
#pragma unroll
  for (int j = 0; j < 8; ++j) {
    x[j] = __expf(x[j] - m);
    s += x[j];
  }
#pragma unroll
  for (int o = 32; o > 0; o >>= 1) s += __shfl_xor(s, o);
  if ((tid & 63) == 0) reds[w] = s;
  __syncthreads();
  s = reds[0] + reds[1] + reds[2] + reds[3];
  const float inv = 1.0f / s;
#pragma unroll
  for (int j = 0; j < 8; ++j) {
    const int k = tid + j * 256;
    const float a = x[j] * inv;
    row[k] = a;
    rowb[k] = f2bf(a);
  }
}

extern "C" void kernel_launch(void* const* d_in, const int* in_sizes, int n_in,
                              void* d_out, int out_size, void* d_ws, size_t ws_size,
                              hipStream_t stream) {
  const float* emb = (const float*)d_in[0];
  const int* mask = (const int*)d_in[1];
  const float* Wq = (const float*)d_in[2];
  const float* Wk = (const float*)d_in[3];
  const float* Wv = (const float*)d_in[4];

  float* out = (float*)d_out;                   // [8,2048,1024] fp32
  float* attn = out + (long long)Bb * Ss * Dd;  // [8,2048,2048] fp32

  char* p = (char*)d_ws;
  u16* emb_hi = (u16*)p;
  u16* emb_lo = emb_hi + (long long)Bb * Ss * Ee;
  u16* attn_bf = emb_hi;  // alias: emb dead before softmax
  u16* q_hi = (u16*)(p + 67108864LL);
  u16* q_lo = q_hi + 16777216LL;
  u16* k_hi = q_lo + 16777216LL;
  u16* k_lo = k_hi + 16777216LL;
  u16* v_t = k_lo + 16777216LL;  // [b][D][S] bf16
  u16* Wq_hi = v_t + 16777216LL;
  u16* Wq_lo = Wq_hi + 1048576LL;
  u16* Wk_hi = Wq_lo + 1048576LL;
  u16* Wk_lo = Wk_hi + 1048576LL;
  u16* Wv_hi = Wk_lo + 1048576LL;

  const float inv_scale = 1.0f / (32.0f + 1.1920929e-07f);

  k_split4<<<16384, 256, 0, stream>>>(emb, emb_hi, emb_lo, (long long)Bb * Ss * Ee / 4);
  k_wt_split<<<dim3(32, 32), 256, 0, stream>>>(Wq, Wq_hi, Wq_lo);
  k_wt_split<<<dim3(32, 32), 256, 0, stream>>>(Wk, Wk_hi, Wk_lo);
  k_wt_split<<<dim3(32, 32), 256, 0, stream>>>(Wv, Wv_hi, nullptr);

  // q = emb @ Wq : M=16384, N=1024, K=1024, split-bf16 output
  k_gemm256<1, false><<<dim3(4, 64, 1), 512, 0, stream>>>(
      emb_hi, emb_lo, Wq_hi, Wq_lo, nullptr, q_hi, q_lo, 1024, 1024, 0, 0, 0);
  k_gemm256<1, false><<<dim3(4, 64, 1), 512, 0, stream>>>(
      emb_hi, emb_lo, Wk_hi, Wk_lo, nullptr, k_hi, k_lo, 1024, 1024, 0, 0, 0);
  // v^T per batch: [D,S] = Wv^T[D,E] x emb_b (BT), single-pass bf16
  k_gemm_bt<2, false><<<dim3(16, 8, 8), 256, 0, stream>>>(
      Wv_hi, emb_hi, nullptr, v_t,
      1024, 2048, 1024, 0, (long long)Ss * Ee, (long long)Dd * Ss);
  // energy per batch: [S,S] = q_b k_b^T, causal tile-skip, fp32 out
  k_gemm256<0, true><<<dim3(8, 8, 8), 512, 0, stream>>>(
      q_hi, q_lo, k_hi, k_lo, attn, nullptr, nullptr,
      2048, 1024, (long long)Ss * Dd, (long long)Ss * Dd, (long long)Ss * Ss);
  // softmax rows in-place + bf16 copy
  k_softmax<<<dim3(Ss, Bb), 256, 0, stream>>>(attn, attn_bf, mask, inv_scale);
  // out per batch: [S,D] = attn_bf @ v (v_t is BT operand), K truncated causally
  k_gemm_bt<0, true><<<dim3(8, 16, 8), 256, 0, stream>>>(
      attn_bf, v_t, out, nullptr,
      2048, 1024, 2048, (long long)Ss * Ss, (long long)Dd * Ss, (long long)Ss * Dd);
}

// Round 3
// 552.544 us; speedup vs baseline: 1.1735x; 1.0876x over previous
//
#include <hip/hip_runtime.h>

#define Bb 8
#define Ss 2048
#define Ee 1024
#define Dd 1024

typedef __attribute__((ext_vector_type(8))) __bf16 bf16x8;
typedef __attribute__((ext_vector_type(4))) float f32x4;
typedef unsigned short u16;

__device__ __forceinline__ u16 f2bf(float x) {
  unsigned u = __float_as_uint(x);
  return (u16)((u + 0x7fffu + ((u >> 16) & 1u)) >> 16);
}
__device__ __forceinline__ float bf2f(u16 h) {
  return __uint_as_float(((unsigned)h) << 16);
}

__device__ __forceinline__ void gload16(const void* g, void* l) {
  __builtin_amdgcn_global_load_lds(
      (__attribute__((address_space(1))) void*)const_cast<void*>(g),
      (__attribute__((address_space(3))) void*)l, 16, 0, 0);
}

#define MFMA_BF16 __builtin_amdgcn_mfma_f32_16x16x32_bf16

// ---------------- fp32 -> bf16 hi/lo split (vectorized x4) ----------------
__global__ __launch_bounds__(256) void k_split4(const float* __restrict__ in,
                                                u16* __restrict__ hi,
                                                u16* __restrict__ lo,
                                                long long n4) {
  long long i = (long long)blockIdx.x * 256 + threadIdx.x;
  if (i >= n4) return;
  float4 v = ((const float4*)in)[i];
  float xs[4] = {v.x, v.y, v.z, v.w};
  u16 hh[4], ll[4];
#pragma unroll
  for (int j = 0; j < 4; ++j) {
    hh[j] = f2bf(xs[j]);
    ll[j] = f2bf(xs[j] - bf2f(hh[j]));
  }
  ushort4 h, l;
  h.x = hh[0]; h.y = hh[1]; h.z = hh[2]; h.w = hh[3];
  l.x = ll[0]; l.y = ll[1]; l.z = ll[2]; l.w = ll[3];
  ((ushort4*)hi)[i] = h;
  ((ushort4*)lo)[i] = l;
}

// ---------------- W [E,D] fp32 -> W^T [D,E] bf16 hi(/lo) ----------------
__global__ __launch_bounds__(256) void k_wt_split(const float* __restrict__ W,
                                                  u16* __restrict__ hi,
                                                  u16* __restrict__ lo) {
  __shared__ float t[32][33];
  const int tx = threadIdx.x & 31;
  const int ty = threadIdx.x >> 5;  // 0..7
  const int e0 = blockIdx.y * 32, d0 = blockIdx.x * 32;
#pragma unroll
  for (int r = ty; r < 32; r += 8)
    t[r][tx] = W[(long long)(e0 + r) * Dd + d0 + tx];
  __syncthreads();
#pragma unroll
  for (int r = ty; r < 32; r += 8) {
    float x = t[tx][r];  // = W[e0+tx][d0+r]
    long long o = (long long)(d0 + r) * Ee + e0 + tx;
    u16 h = f2bf(x);
    hi[o] = h;
    if (lo) lo[o] = f2bf(x - bf2f(h));
  }
}

// ============ deep-prefetch 256x256 split-precision BT GEMM (proj) ========
// C[M,N] = (Ah+Al)(Bh+Bl)^T (drop Al*Bl).  8 waves (2Mx4N), per-wave 128x64,
// BK=32, dbuf LDS 128KiB.  Per tile: burst-stage 8 loads for tile kt+1,
// vmcnt(8) [full-tile pipeline lead], then 3 read-phases / 4 MFMA clusters
// with m201-style {BAR; reads; BAR; setprio MFMA} interleave.
// Flat 1D grid with XCD-chunk swizzle (nwg % 8 == 0 required).
template <int EPI>  // 0 = fp32 store, 1 = split hi/lo bf16 store
__global__ __launch_bounds__(512, 2) void k_gemm256(
    const u16* __restrict__ Ah, const u16* __restrict__ Al,
    const u16* __restrict__ Bh, const u16* __restrict__ Bl,
    float* __restrict__ Cf, u16* __restrict__ Ch, u16* __restrict__ Cl,
    int nbx, int N, int K) {
  const int nwg = gridDim.x;
  const int f = blockIdx.x;
  const int wgid = (f & 7) * (nwg >> 3) + (f >> 3);  // XCD chunk swizzle
  const int bx = wgid % nbx;
  const int by = wgid / nbx;

  // lds[buf][mat][8192 u16]; mat: 0=Ah 1=Al 2=Bh 3=Bl; 256 rows x 32 bf16,
  // 64B rows of 4x16B chunks, chunk XOR-swizzled by (row>>1)&3.
  __shared__ __align__(16) u16 lds[2][4][8192];

  const int tid = threadIdx.x;
  const int lane = tid & 63;
  const int w = tid >> 6;  // 0..7
  const int wr = w >> 2;   // 0..1
  const int wc = w & 3;    // 0..3

  const u16* srcBase[4] = {Ah, Al, Bh, Bl};
  const long long row0[2] = {(long long)by * 256, (long long)bx * 256};

  const int rL = tid >> 2;  // 0..127
  const int colOff = ((tid & 3) ^ ((tid >> 3) & 3)) * 8;
  const int rdOff = (lane & 15) * 64 + ((((lane >> 4) & 3) ^ ((lane >> 1) & 3)) << 4);

  const int AR = wr * 128;
  const int BR = wc * 64;
  const int nt = K / 32;

#define STAGE8(buf, kt)                                                 \
  {                                                                     \
    _Pragma("unroll") for (int u = 0; u < 8; ++u) {                     \
      const int mat = u >> 1, half = u & 1;                             \
      const long long grow = row0[mat >> 1] + half * 128 + rL;          \
      gload16(srcBase[mat] + grow * K + (kt)*32 + colOff,               \
              (char*)&lds[buf][mat][0] + half * 8192 + w * 1024);       \
    }                                                                   \
  }
#define LDFRAG(buf, mat, R) \
  (*(const bf16x8*)((const char*)&lds[buf][mat][0] + (R)*64 + rdOff))

  f32x4 acc[8][4];
#pragma unroll
  for (int m = 0; m < 8; ++m)
#pragma unroll
    for (int n = 0; n < 4; ++n) acc[m][n] = f32x4{0.f, 0.f, 0.f, 0.f};

  bf16x8 a_h[4], a_l[4], b_h[4], b_l[4];

  STAGE8(0, 0);  // prologue

  for (int kt = 0; kt < nt; ++kt) {
    const int cur = kt & 1;
    const bool more = (kt + 1 < nt);

    if (more) {
      STAGE8(cur ^ 1, kt + 1);
      asm volatile("s_waitcnt vmcnt(8)" ::: "memory");
    } else {
      asm volatile("s_waitcnt vmcnt(0)" ::: "memory");
    }
    __builtin_amdgcn_s_barrier();  // A: tile-kt data ready; prev reads done

    // phase 0 reads: A m0-3 hi/lo + B n0-1 hi/lo (12)
#pragma unroll
    for (int m = 0; m < 4; ++m) {
      a_h[m] = LDFRAG(cur, 0, AR + m * 16);
      a_l[m] = LDFRAG(cur, 1, AR + m * 16);
    }
#pragma unroll
    for (int n = 0; n < 2; ++n) {
      b_h[n] = LDFRAG(cur, 2, BR + n * 16);
      b_l[n] = LDFRAG(cur, 3, BR + n * 16);
    }
    __builtin_amdgcn_s_barrier();  // B
    __builtin_amdgcn_s_setprio(1);
#pragma unroll
    for (int m = 0; m < 4; ++m)
#pragma unroll
      for (int n = 0; n < 2; ++n) {
        acc[m][n] = MFMA_BF16(a_h[m], b_l[n], acc[m][n], 0, 0, 0);
        acc[m][n] = MFMA_BF16(a_l[m], b_h[n], acc[m][n], 0, 0, 0);
        acc[m][n] = MFMA_BF16(a_h[m], b_h[n], acc[m][n], 0, 0, 0);
      }
    __builtin_amdgcn_s_setprio(0);
    __builtin_amdgcn_s_barrier();  // C

    // phase 1 reads: B n2-3 hi/lo (4)
#pragma unroll
    for (int n = 2; n < 4; ++n) {
      b_h[n] = LDFRAG(cur, 2, BR + n * 16);
      b_l[n] = LDFRAG(cur, 3, BR + n * 16);
    }
    __builtin_amdgcn_s_barrier();  // D
    __builtin_amdgcn_s_setprio(1);
#pragma unroll
    for (int m = 0; m < 4; ++m)
#pragma unroll
      for (int n = 2; n < 4; ++n) {
        acc[m][n] = MFMA_BF16(a_h[m], b_l[n], acc[m][n], 0, 0, 0);
        acc[m][n] = MFMA_BF16(a_l[m], b_h[n], acc[m][n], 0, 0, 0);
        acc[m][n] = MFMA_BF16(a_h[m], b_h[n], acc[m][n], 0, 0, 0);
      }
    __builtin_amdgcn_s_setprio(0);
    __builtin_amdgcn_s_barrier();  // E

    // phase 2 reads: A m4-7 hi/lo (8, reuse regs)
#pragma unroll
    for (int m = 0; m < 4; ++m) {
      a_h[m] = LDFRAG(cur, 0, AR + 64 + m * 16);
      a_l[m] = LDFRAG(cur, 1, AR + 64 + m * 16);
    }
    __builtin_amdgcn_s_barrier();  // F
    __builtin_amdgcn_s_setprio(1);
#pragma unroll
    for (int m = 0; m < 4; ++m)
#pragma unroll
      for (int n = 0; n < 4; ++n) {
        acc[4 + m][n] = MFMA_BF16(a_h[m], b_l[n], acc[4 + m][n], 0, 0, 0);
        acc[4 + m][n] = MFMA_BF16(a_l[m], b_h[n], acc[4 + m][n], 0, 0, 0);
        acc[4 + m][n] = MFMA_BF16(a_h[m], b_h[n], acc[4 + m][n], 0, 0, 0);
      }
    __builtin_amdgcn_s_setprio(0);
    __builtin_amdgcn_s_barrier();  // G: all reads of buf cur drained
  }

  // epilogue: C/D map col=lane&15, row=(lane>>4)*4+reg
  const int cr = (lane >> 4) << 2;
  const int cc = lane & 15;
#pragma unroll
  for (int m = 0; m < 8; ++m)
#pragma unroll
    for (int n = 0; n < 4; ++n)
#pragma unroll
      for (int r = 0; r < 4; ++r) {
        const long long row = (long long)by * 256 + wr * 128 + m * 16 + cr + r;
        const long long col = (long long)bx * 256 + wc * 64 + n * 16 + cc;
        const long long idx = row * N + col;
        const float v = acc[m][n][r];
        if constexpr (EPI == 0) {
          Cf[idx] = v;
        } else {
          u16 h = f2bf(v);
          Ch[idx] = h;
          Cl[idx] = f2bf(v - bf2f(h));
        }
      }
#undef STAGE8
#undef LDFRAG
}

// ============ deep-prefetch 128x128 energy GEMM (4 waves, 2 blk/CU) =======
// energy_b = q_b k_b^T, split-precision 3-pass, causal tile set only.
// 1088 = 8 batches x 136 lower-triangle tiles; XCD swizzle -> 1 batch/XCD.
__global__ __launch_bounds__(256, 2) void k_energy128(
    const u16* __restrict__ qh, const u16* __restrict__ ql,
    const u16* __restrict__ kh, const u16* __restrict__ kl,
    float* __restrict__ attn) {
  const int nwg = gridDim.x;  // 1088
  const int f = blockIdx.x;
  const int wgid = (f & 7) * (nwg >> 3) + (f >> 3);
  const int bz = wgid / 136;
  const int t = wgid % 136;
  int by = 0, c = 0;
  while (c + by + 1 <= t) { c += by + 1; ++by; }  // <=16 iters
  const int bx = t - c;

  __shared__ __align__(16) u16 lds[2][4][4096];  // 64 KiB -> 2 blocks/CU

  const int tid = threadIdx.x;
  const int lane = tid & 63;
  const int w = tid >> 6;  // 0..3
  const int wr = w >> 1;   // 0..1
  const int wc = w & 1;    // 0..1

  const long long sQ = (long long)bz * Ss * Dd;
  const u16* srcBase[4] = {qh + sQ, ql + sQ, kh + sQ, kl + sQ};
  const long long row0[2] = {(long long)by * 128, (long long)bx * 128};

  const int rL = tid >> 2;  // 0..63
  const int colOff = ((tid & 3) ^ ((tid >> 3) & 3)) * 8;
  const int rdOff = (lane & 15) * 64 + ((((lane >> 4) & 3) ^ ((lane >> 1) & 3)) << 4);

  const int AR = wr * 64;
  const int BR = wc * 64;
  const int nt = Dd / 32;  // 32

#define STAGE8E(buf, kt)                                                \
  {                                                                     \
    _Pragma("unroll") for (int u = 0; u < 8; ++u) {                     \
      const int mat = u >> 1, half = u & 1;                             \
      const long long grow = row0[mat >> 1] + half * 64 + rL;           \
      gload16(srcBase[mat] + grow * Dd + (kt)*32 + colOff,              \
              (char*)&lds[buf][mat][0] + half * 4096 + w * 1024);       \
    }                                                                   \
  }
#define LDFRAGE(buf, mat, R) \
  (*(const bf16x8*)((const char*)&lds[buf][mat][0] + (R)*64 + rdOff))

  f32x4 acc[4][4];
#pragma unroll
  for (int m = 0; m < 4; ++m)
#pragma unroll
    for (int n = 0; n < 4; ++n) acc[m][n] = f32x4{0.f, 0.f, 0.f, 0.f};

  bf16x8 a_h[4], a_l[4], b_h[4], b_l[4];

  STAGE8E(0, 0);

  for (int kt = 0; kt < nt; ++kt) {
    const int cur = kt & 1;
    const bool more = (kt + 1 < nt);

    if (more) {
      STAGE8E(cur ^ 1, kt + 1);
      asm volatile("s_waitcnt vmcnt(8)" ::: "memory");
    } else {
      asm volatile("s_waitcnt vmcnt(0)" ::: "memory");
    }
    __builtin_amdgcn_s_barrier();  // data ready

    // phase 0 reads: A m0-3 hi/lo + B n0-1 hi/lo
#pragma unroll
    for (int m = 0; m < 4; ++m) {
      a_h[m] = LDFRAGE(cur, 0, AR + m * 16);
      a_l[m] = LDFRAGE(cur, 1, AR + m * 16);
    }
#pragma unroll
    for (int n = 0; n < 2; ++n) {
      b_h[n] = LDFRAGE(cur, 2, BR + n * 16);
      b_l[n] = LDFRAGE(cur, 3, BR + n * 16);
    }
    __builtin_amdgcn_s_barrier();
    __builtin_amdgcn_s_setprio(1);
#pragma unroll
    for (int m = 0; m < 4; ++m)
#pragma unroll
      for (int n = 0; n < 2; ++n) {
        acc[m][n] = MFMA_BF16(a_h[m], b_l[n], acc[m][n], 0, 0, 0);
        acc[m][n] = MFMA_BF16(a_l[m], b_h[n], acc[m][n], 0, 0, 0);
        acc[m][n] = MFMA_BF16(a_h[m], b_h[n], acc[m][n], 0, 0, 0);
      }
    __builtin_amdgcn_s_setprio(0);
    __builtin_amdgcn_s_barrier();

    // phase 1 reads: B n2-3 hi/lo
#pragma unroll
    for (int n = 2; n < 4; ++n) {
      b_h[n] = LDFRAGE(cur, 2, BR + n * 16);
      b_l[n] = LDFRAGE(cur, 3, BR + n * 16);
    }
    __builtin_amdgcn_s_barrier();
    __builtin_amdgcn_s_setprio(1);
#pragma unroll
    for (int m = 0; m < 4; ++m)
#pragma unroll
      for (int n = 2; n < 4; ++n) {
        acc[m][n] = MFMA_BF16(a_h[m], b_l[n], acc[m][n], 0, 0, 0);
        acc[m][n] = MFMA_BF16(a_l[m], b_h[n], acc[m][n], 0, 0, 0);
        acc[m][n] = MFMA_BF16(a_h[m], b_h[n], acc[m][n], 0, 0, 0);
      }
    __builtin_amdgcn_s_setprio(0);
    __builtin_amdgcn_s_barrier();  // reads drained before next stage
  }

  const int cr = (lane >> 4) << 2;
  const int cc = lane & 15;
#pragma unroll
  for (int m = 0; m < 4; ++m)
#pragma unroll
    for (int n = 0; n < 4; ++n)
#pragma unroll
      for (int r = 0; r < 4; ++r) {
        const long long row = (long long)by * 128 + wr * 64 + m * 16 + cr + r;
        const long long col = (long long)bx * 128 + wc * 64 + n * 16 + cc;
        attn[(long long)bz * Ss * Ss + row * Ss + col] = acc[m][n][r];
      }
#undef STAGE8E
#undef LDFRAGE
}

// ---------------- 128x128-tile BT-layout MFMA GEMM (NPASS=1) --------------
// EPI: 0 = fp32 store; 2 = bf16 store.  TRIK: truncate K at (by+1)*128.
template <int EPI, bool TRIK>
__global__ __launch_bounds__(256) void k_gemm_bt(
    const u16* __restrict__ Ah, const u16* __restrict__ Bh,
    float* __restrict__ Cf, u16* __restrict__ Ch,
    int M, int N, int K, long long strA, long long strB, long long strC) {
  const int bx = blockIdx.x, by = blockIdx.y, bz = blockIdx.z;

  const int tid = threadIdx.x;
  const int lane = tid & 63;
  const int w = tid >> 6;
  const int wr = w >> 1, wc = w & 1;

  const u16* pAh = Ah + (long long)bz * strA;
  const u16* pBh = Bh + (long long)bz * strB;

  __shared__ __align__(16) u16 lds[2 * 128 * 32];
  char* ldsc = (char*)lds;

  const int srow = tid >> 2;
  const int scol = (tid & 3) * 8;
  const long long arow = (long long)by * 128 + srow;
  const long long brow = (long long)bx * 128 + srow;

  int ktEnd = K / 32;
  if (TRIK) {
    int lim = ((by + 1) * 128) / 32;
    if (lim < ktEnd) ktEnd = lim;
  }

  f32x4 acc[4][4];
#pragma unroll
  for (int i = 0; i < 4; ++i)
#pragma unroll
    for (int j = 0; j < 4; ++j) acc[i][j] = f32x4{0.f, 0.f, 0.f, 0.f};

  for (int kt = 0; kt < ktEnd; ++kt) {
    const int k0 = kt * 32 + scol;
    __syncthreads();
    gload16(pAh + arow * K + k0, ldsc + 0 * 4096 + w * 1024);
    gload16(pAh + (arow + 64) * K + k0, ldsc + 1 * 4096 + w * 1024);
    gload16(pBh + brow * K + k0, ldsc + 8192 + 0 * 4096 + w * 1024);
    gload16(pBh + (brow + 64) * K + k0, ldsc + 8192 + 1 * 4096 + w * 1024);
    __syncthreads();

    const int kk = (lane >> 4) * 8;
    const int ar = wr * 64 + (lane & 15);
    const int br = wc * 64 + (lane & 15);
    bf16x8 avh[4], bvh[4];
#pragma unroll
    for (int m = 0; m < 4; ++m)
      avh[m] = *(const bf16x8*)(lds + (ar + m * 16) * 32 + kk);
#pragma unroll
    for (int n = 0; n < 4; ++n)
      bvh[n] = *(const bf16x8*)(lds + 128 * 32 + (br + n * 16) * 32 + kk);
#pragma unroll
    for (int m = 0; m < 4; ++m)
#pragma unroll
      for (int n = 0; n < 4; ++n)
        acc[m][n] = MFMA_BF16(avh[m], bvh[n], acc[m][n], 0, 0, 0);
  }

  const int cr = wr * 64 + ((lane >> 4) << 2);
  const int cc = wc * 64 + (lane & 15);
  const long long rb = (long long)by * 128 + cr;
  const long long cb = (long long)bx * 128 + cc;
#pragma unroll
  for (int m = 0; m < 4; ++m)
#pragma unroll
    for (int n = 0; n < 4; ++n)
#pragma unroll
      for (int r = 0; r < 4; ++r) {
        const long long idx =
            (long long)bz * strC + (rb + m * 16 + r) * (long long)N + (cb + n * 16);
        const float v = acc[m][n][r];
        if constexpr (EPI == 0) Cf[idx] = v;
        else Ch[idx] = f2bf(v);
      }
}

// ---------------- causal+pad masked row softmax (in-place) ----------------
__global__ __launch_bounds__(256) void k_softmax(float* __restrict__ attn,
                                                 u16* __restrict__ attn_bf,
                                                 const int* __restrict__ mask,
                                                 float inv_scale) {
  const int q = blockIdx.x;
  const int b = blockIdx.y;
  const int tid = threadIdx.x;
  float* row = attn + ((long long)b * Ss + q) * Ss;
  u16* rowb = attn_bf + ((long long)b * Ss + q) * Ss;
  const int* mrow = mask + b * Ss;

  float x[8];
  float m = -3.0e38f;
#pragma unroll
  for (int j = 0; j < 8; ++j) {
    const int k = tid + j * 256;
    const float e = row[k];
    const bool ok = (k <= q) && (mrow[k] != 0);
    const float v = (ok ? e : -1e20f) * inv_scale;
    x[j] = v;
    m = fmaxf(m, v);
  }
#pragma unroll
  for (int o = 32; o > 0; o >>= 1) m = fmaxf(m, __shfl_xor(m, o));
  __shared__ float redm[4], reds[4];
  const int w = tid >> 6;
  if ((tid & 63) == 0) redm[w] = m;
  __syncthreads();
  m = fmaxf(fmaxf(redm[0], redm[1]), fmaxf(redm[2], redm[3]));
  float s = 0.f;
#pragma unroll
  for (int j = 0; j < 8; ++j) {
    x[j] = __expf(x[j] - m);
    s += x[j];
  }
#pragma unroll
  for (int o = 32; o > 0; o >>= 1) s += __shfl_xor(s, o);
  if ((tid & 63) == 0) reds[w] = s;
  __syncthreads();
  s = reds[0] + reds[1] + reds[2] + reds[3];
  const float inv = 1.0f / s;
#pragma unroll
  for (int j = 0; j < 8; ++j) {
    const int k = tid + j * 256;
    const float a = x[j] * inv;
    row[k] = a;
    rowb[k] = f2bf(a);
  }
}

extern "C" void kernel_launch(void* const* d_in, const int* in_sizes, int n_in,
                              void* d_out, int out_size, void* d_ws, size_t ws_size,
                              hipStream_t stream) {
  const float* emb = (const float*)d_in[0];
  const int* mask = (const int*)d_in[1];
  const float* Wq = (const float*)d_in[2];
  const float* Wk = (const float*)d_in[3];
  const float* Wv = (const float*)d_in[4];

  float* out = (float*)d_out;                   // [8,2048,1024] fp32
  float* attn = out + (long long)Bb * Ss * Dd;  // [8,2048,2048] fp32

  char* p = (char*)d_ws;
  u16* emb_hi = (u16*)p;
  u16* emb_lo = emb_hi + (long long)Bb * Ss * Ee;
  u16* attn_bf = emb_hi;  // alias: emb dead before softmax
  u16* q_hi = (u16*)(p + 67108864LL);
  u16* q_lo = q_hi + 16777216LL;
  u16* k_hi = q_lo + 16777216LL;
  u16* k_lo = k_hi + 16777216LL;
  u16* v_t = k_lo + 16777216LL;  // [b][D][S] bf16
  u16* Wq_hi = v_t + 16777216LL;
  u16* Wq_lo = Wq_hi + 1048576LL;
  u16* Wk_hi = Wq_lo + 1048576LL;
  u16* Wk_lo = Wk_hi + 1048576LL;
  u16* Wv_hi = Wk_lo + 1048576LL;

  const float inv_scale = 1.0f / (32.0f + 1.1920929e-07f);

  k_split4<<<16384, 256, 0, stream>>>(emb, emb_hi, emb_lo, (long long)Bb * Ss * Ee / 4);
  k_wt_split<<<dim3(32, 32), 256, 0, stream>>>(Wq, Wq_hi, Wq_lo);
  k_wt_split<<<dim3(32, 32), 256, 0, stream>>>(Wk, Wk_hi, Wk_lo);
  k_wt_split<<<dim3(32, 32), 256, 0, stream>>>(Wv, Wv_hi, nullptr);

  // q/k = emb @ W : M=16384, N=1024, K=1024; flat grid 256 (nbx=4)
  k_gemm256<1><<<256, 512, 0, stream>>>(
      emb_hi, emb_lo, Wq_hi, Wq_lo, nullptr, q_hi, q_lo, 4, 1024, 1024);
  k_gemm256<1><<<256, 512, 0, stream>>>(
      emb_hi, emb_lo, Wk_hi, Wk_lo, nullptr, k_hi, k_lo, 4, 1024, 1024);
  // v^T per batch: [D,S] = Wv^T[D,E] x emb_b (BT), single-pass bf16
  k_gemm_bt<2, false><<<dim3(16, 8, 8), 256, 0, stream>>>(
      Wv_hi, emb_hi, nullptr, v_t,
      1024, 2048, 1024, 0, (long long)Ss * Ee, (long long)Dd * Ss);
  // energy: 128^2 causal tiles, 4-wave 2-blk/CU deep-prefetch
  k_energy128<<<1088, 256, 0, stream>>>(q_hi, q_lo, k_hi, k_lo, attn);
  // softmax rows in-place + bf16 copy
  k_softmax<<<dim3(Ss, Bb), 256, 0, stream>>>(attn, attn_bf, mask, inv_scale);
  // out per batch: [S,D] = attn_bf @ v (v_t is BT operand), K truncated causally
  k_gemm_bt<0, true><<<dim3(8, 16, 8), 256, 0, stream>>>(
      attn_bf, v_t, out, nullptr,
      2048, 1024, 2048, (long long)Ss * Ss, (long long)Dd * Ss, (long long)Ss * Dd);
}

// Round 4
// 543.453 us; speedup vs baseline: 1.1931x; 1.0167x over previous
//
#include <hip/hip_runtime.h>

#define Bb 8
#define Ss 2048
#define Ee 1024
#define Dd 1024

typedef __attribute__((ext_vector_type(8))) __bf16 bf16x8;
typedef __attribute__((ext_vector_type(4))) float f32x4;
typedef unsigned short u16;

__device__ __forceinline__ u16 f2bf(float x) {
  unsigned u = __float_as_uint(x);
  return (u16)((u + 0x7fffu + ((u >> 16) & 1u)) >> 16);
}
__device__ __forceinline__ float bf2f(u16 h) {
  return __uint_as_float(((unsigned)h) << 16);
}

__device__ __forceinline__ void gload16(const void* g, void* l) {
  __builtin_amdgcn_global_load_lds(
      (__attribute__((address_space(1))) void*)const_cast<void*>(g),
      (__attribute__((address_space(3))) void*)l, 16, 0, 0);
}

#define MFMA_BF16 __builtin_amdgcn_mfma_f32_16x16x32_bf16

// ---------------- fp32 -> bf16 hi/lo split (vectorized x4) ----------------
__global__ __launch_bounds__(256) void k_split4(const float* __restrict__ in,
                                                u16* __restrict__ hi,
                                                u16* __restrict__ lo,
                                                long long n4) {
  long long i = (long long)blockIdx.x * 256 + threadIdx.x;
  if (i >= n4) return;
  float4 v = ((const float4*)in)[i];
  float xs[4] = {v.x, v.y, v.z, v.w};
  u16 hh[4], ll[4];
#pragma unroll
  for (int j = 0; j < 4; ++j) {
    hh[j] = f2bf(xs[j]);
    ll[j] = f2bf(xs[j] - bf2f(hh[j]));
  }
  ushort4 h, l;
  h.x = hh[0]; h.y = hh[1]; h.z = hh[2]; h.w = hh[3];
  l.x = ll[0]; l.y = ll[1]; l.z = ll[2]; l.w = ll[3];
  ((ushort4*)hi)[i] = h;
  ((ushort4*)lo)[i] = l;
}

// ---------------- W [E,D] fp32 -> W^T [D,E] bf16 hi(/lo) ----------------
__global__ __launch_bounds__(256) void k_wt_split(const float* __restrict__ W,
                                                  u16* __restrict__ hi,
                                                  u16* __restrict__ lo) {
  __shared__ float t[32][33];
  const int tx = threadIdx.x & 31;
  const int ty = threadIdx.x >> 5;  // 0..7
  const int e0 = blockIdx.y * 32, d0 = blockIdx.x * 32;
#pragma unroll
  for (int r = ty; r < 32; r += 8)
    t[r][tx] = W[(long long)(e0 + r) * Dd + d0 + tx];
  __syncthreads();
#pragma unroll
  for (int r = ty; r < 32; r += 8) {
    float x = t[tx][r];  // = W[e0+tx][d0+r]
    long long o = (long long)(d0 + r) * Ee + e0 + tx;
    u16 h = f2bf(x);
    hi[o] = h;
    if (lo) lo[o] = f2bf(x - bf2f(h));
  }
}

// ======= fine-interleaved 8-phase 256x256 split-precision BT GEMM =========
// C[M,N] = (Ah+Al)(Bh+Bl)^T (drop Al*Bl).  8 waves (2Mx4N), per-wave 128x64,
// BK=32, dbuf LDS 128KiB.  Per K-tile: 8 phases of {ds_read subtile; 2x
// global_load_lds; BAR; setprio 12-MFMA cluster setprio; BAR}; staging spread
// 2/phase; vmcnt(2)+BAR once per tile (full-tile pipeline lead); per-thread
// global pointers advanced +64B/tile.  Chunk-XOR LDS swizzle both sides.
template <int EPI>  // 0 = fp32 store, 1 = split hi/lo bf16 store
__global__ __launch_bounds__(512, 2) void k_gemm256(
    const u16* __restrict__ Ah, const u16* __restrict__ Al,
    const u16* __restrict__ Bh, const u16* __restrict__ Bl,
    float* __restrict__ Cf, u16* __restrict__ Ch, u16* __restrict__ Cl,
    int nbx, int N, int K) {
  const int nwg = gridDim.x;
  const int f = blockIdx.x;
  const int wgid = (f & 7) * (nwg >> 3) + (f >> 3);  // XCD chunk swizzle
  const int bx = wgid % nbx;
  const int by = wgid / nbx;

  // lds[buf][mat][8192 u16]; mat: 0=Ah 1=Al 2=Bh 3=Bl; 256 rows x 32 bf16,
  // 64B rows of 4x16B chunks, chunk XOR-swizzled by (row>>1)&3.
  __shared__ __align__(16) u16 lds[2][4][8192];

  const int tid = threadIdx.x;
  const int lane = tid & 63;
  const int w = tid >> 6;  // 0..7
  const int wr = w >> 2;   // 0..1
  const int wc = w & 3;    // 0..3

  const u16* srcBase[4] = {Ah, Al, Bh, Bl};
  const long long row0[2] = {(long long)by * 256, (long long)bx * 256};

  const int rL = tid >> 2;  // 0..127
  const int colOff = ((tid & 3) ^ ((tid >> 3) & 3)) * 8;
  const int rdOff = (lane & 15) * 64 + ((((lane >> 4) & 3) ^ ((lane >> 1) & 3)) << 4);

  const int AR = wr * 128;
  const int BR = wc * 64;
  const int nt = K / 32;

  // per-thread staging pointers (advance +32 u16 = 64B per K-tile)
  const u16* gp[8];
#pragma unroll
  for (int u = 0; u < 8; ++u) {
    const int mat = u >> 1, half = u & 1;
    const long long grow = row0[mat >> 1] + half * 128 + rL;
    gp[u] = srcBase[mat] + grow * (long long)K + colOff;
  }

#define GL(U)                                                              \
  do {                                                                     \
    gload16(gp[U], (char*)lds + (cur ^ 1) * 65536 + ((U) >> 1) * 16384 +   \
                       ((U)&1) * 8192 + w * 1024);                         \
    gp[U] += 32;                                                           \
  } while (0)

#define LDFRAG(mat, R) \
  (*(const bf16x8*)((const char*)&lds[cur][mat][0] + (R)*64 + rdOff))

#define RD_A(MH)                                      \
  _Pragma("unroll") for (int m = 0; m < 4; ++m) {     \
    aH[MH][m] = LDFRAG(0, AR + (MH)*64 + m * 16);     \
    aL[MH][m] = LDFRAG(1, AR + (MH)*64 + m * 16);     \
  }

#define RD_B(NI)                      \
  bH = LDFRAG(2, BR + (NI)*16);       \
  bL = LDFRAG(3, BR + (NI)*16);

#define CLUSTER(MH, NI)                                                          \
  __builtin_amdgcn_s_setprio(1);                                                 \
  _Pragma("unroll") for (int m = 0; m < 4; ++m)                                  \
      acc[(MH)*4 + m][NI] = MFMA_BF16(aH[MH][m], bL, acc[(MH)*4 + m][NI], 0, 0, 0); \
  _Pragma("unroll") for (int m = 0; m < 4; ++m)                                  \
      acc[(MH)*4 + m][NI] = MFMA_BF16(aL[MH][m], bH, acc[(MH)*4 + m][NI], 0, 0, 0); \
  _Pragma("unroll") for (int m = 0; m < 4; ++m)                                  \
      acc[(MH)*4 + m][NI] = MFMA_BF16(aH[MH][m], bH, acc[(MH)*4 + m][NI], 0, 0, 0); \
  __builtin_amdgcn_s_setprio(0);

#define BAR __builtin_amdgcn_s_barrier()

  f32x4 acc[8][4];
#pragma unroll
  for (int m = 0; m < 8; ++m)
#pragma unroll
    for (int n = 0; n < 4; ++n) acc[m][n] = f32x4{0.f, 0.f, 0.f, 0.f};

  bf16x8 aH[2][4], aL[2][4], bH, bL;

  // prologue: stage tile 0 fully (8 loads) into buf 0
  {
    const int cur = 1;  // so cur^1 == 0
#pragma unroll
    for (int u = 0; u < 8; ++u) GL(u);
  }

  for (int kt = 0; kt < nt; ++kt) {
    const int cur = kt & 1;
    const bool more = (kt + 1 < nt);

    // ---- tile gate: issue first stage pair, count-wait own, sync all ----
    if (more) {
      GL(0); GL(1);
      asm volatile("s_waitcnt vmcnt(2)" ::: "memory");
    } else {
      asm volatile("s_waitcnt vmcnt(0)" ::: "memory");
    }
    BAR;  // all waves' tile-kt staging landed; prev-tile reads long done

    // P0: A-mh0 + B-n0 (10 reads); MFMA (0,0)
    RD_A(0); RD_B(0);
    BAR; CLUSTER(0, 0); BAR;
    // P1: A-mh1 (8 reads); stage pair; MFMA (1,0)
    RD_A(1);
    if (more) { GL(2); GL(3); }
    BAR; CLUSTER(1, 0); BAR;
    // P2: B-n1; stage pair; MFMA (0,1)
    RD_B(1);
    if (more) { GL(4); GL(5); }
    BAR; CLUSTER(0, 1); BAR;
    // P3: stage pair; MFMA (1,1)
    if (more) { GL(6); GL(7); }
    BAR; CLUSTER(1, 1); BAR;
    // P4: B-n2; MFMA (0,2)
    RD_B(2);
    BAR; CLUSTER(0, 2); BAR;
    // P5: MFMA (1,2)
    CLUSTER(1, 2); BAR;
    // P6: B-n3; MFMA (0,3)
    RD_B(3);
    BAR; CLUSTER(0, 3); BAR;
    // P7: MFMA (1,3)
    CLUSTER(1, 3); BAR;
  }

  // epilogue: C/D map col=lane&15, row=(lane>>4)*4+reg
  const int cr = (lane >> 4) << 2;
  const int cc = lane & 15;
#pragma unroll
  for (int m = 0; m < 8; ++m)
#pragma unroll
    for (int n = 0; n < 4; ++n)
#pragma unroll
      for (int r = 0; r < 4; ++r) {
        const long long row = (long long)by * 256 + wr * 128 + m * 16 + cr + r;
        const long long col = (long long)bx * 256 + wc * 64 + n * 16 + cc;
        const long long idx = row * N + col;
        const float v = acc[m][n][r];
        if constexpr (EPI == 0) {
          Cf[idx] = v;
        } else {
          u16 h = f2bf(v);
          Ch[idx] = h;
          Cl[idx] = f2bf(v - bf2f(h));
        }
      }
#undef GL
#undef LDFRAG
#undef RD_A
#undef RD_B
#undef CLUSTER
#undef BAR
}

// ============ deep-prefetch 128x128 energy GEMM (4 waves, 2 blk/CU) =======
// energy_b = q_b k_b^T, split-precision 3-pass, causal tile set only.
// 1088 = 8 batches x 136 lower-triangle tiles; XCD swizzle -> 1 batch/XCD.
__global__ __launch_bounds__(256, 2) void k_energy128(
    const u16* __restrict__ qh, const u16* __restrict__ ql,
    const u16* __restrict__ kh, const u16* __restrict__ kl,
    float* __restrict__ attn) {
  const int nwg = gridDim.x;  // 1088
  const int f = blockIdx.x;
  const int wgid = (f & 7) * (nwg >> 3) + (f >> 3);
  const int bz = wgid / 136;
  const int t = wgid % 136;
  int by = 0, c = 0;
  while (c + by + 1 <= t) { c += by + 1; ++by; }  // <=16 iters
  const int bx = t - c;

  __shared__ __align__(16) u16 lds[2][4][4096];  // 64 KiB -> 2 blocks/CU

  const int tid = threadIdx.x;
  const int lane = tid & 63;
  const int w = tid >> 6;  // 0..3
  const int wr = w >> 1;   // 0..1
  const int wc = w & 1;    // 0..1

  const long long sQ = (long long)bz * Ss * Dd;
  const u16* srcBase[4] = {qh + sQ, ql + sQ, kh + sQ, kl + sQ};
  const long long row0[2] = {(long long)by * 128, (long long)bx * 128};

  const int rL = tid >> 2;  // 0..63
  const int colOff = ((tid & 3) ^ ((tid >> 3) & 3)) * 8;
  const int rdOff = (lane & 15) * 64 + ((((lane >> 4) & 3) ^ ((lane >> 1) & 3)) << 4);

  const int AR = wr * 64;
  const int BR = wc * 64;
  const int nt = Dd / 32;  // 32

#define STAGE8E(buf, kt)                                                \
  {                                                                     \
    _Pragma("unroll") for (int u = 0; u < 8; ++u) {                     \
      const int mat = u >> 1, half = u & 1;                             \
      const long long grow = row0[mat >> 1] + half * 64 + rL;           \
      gload16(srcBase[mat] + grow * Dd + (kt)*32 + colOff,              \
              (char*)&lds[buf][mat][0] + half * 4096 + w * 1024);       \
    }                                                                   \
  }
#define LDFRAGE(buf, mat, R) \
  (*(const bf16x8*)((const char*)&lds[buf][mat][0] + (R)*64 + rdOff))

  f32x4 acc[4][4];
#pragma unroll
  for (int m = 0; m < 4; ++m)
#pragma unroll
    for (int n = 0; n < 4; ++n) acc[m][n] = f32x4{0.f, 0.f, 0.f, 0.f};

  bf16x8 a_h[4], a_l[4], b_h[4], b_l[4];

  STAGE8E(0, 0);

  for (int kt = 0; kt < nt; ++kt) {
    const int cur = kt & 1;
    const bool more = (kt + 1 < nt);

    if (more) {
      STAGE8E(cur ^ 1, kt + 1);
      asm volatile("s_waitcnt vmcnt(8)" ::: "memory");
    } else {
      asm volatile("s_waitcnt vmcnt(0)" ::: "memory");
    }
    __builtin_amdgcn_s_barrier();  // data ready

    // phase 0 reads: A m0-3 hi/lo + B n0-1 hi/lo
#pragma unroll
    for (int m = 0; m < 4; ++m) {
      a_h[m] = LDFRAGE(cur, 0, AR + m * 16);
      a_l[m] = LDFRAGE(cur, 1, AR + m * 16);
    }
#pragma unroll
    for (int n = 0; n < 2; ++n) {
      b_h[n] = LDFRAGE(cur, 2, BR + n * 16);
      b_l[n] = LDFRAGE(cur, 3, BR + n * 16);
    }
    __builtin_amdgcn_s_barrier();
    __builtin_amdgcn_s_setprio(1);
#pragma unroll
    for (int m = 0; m < 4; ++m)
#pragma unroll
      for (int n = 0; n < 2; ++n) {
        acc[m][n] = MFMA_BF16(a_h[m], b_l[n], acc[m][n], 0, 0, 0);
        acc[m][n] = MFMA_BF16(a_l[m], b_h[n], acc[m][n], 0, 0, 0);
        acc[m][n] = MFMA_BF16(a_h[m], b_h[n], acc[m][n], 0, 0, 0);
      }
    __builtin_amdgcn_s_setprio(0);
    __builtin_amdgcn_s_barrier();

    // phase 1 reads: B n2-3 hi/lo
#pragma unroll
    for (int n = 2; n < 4; ++n) {
      b_h[n] = LDFRAGE(cur, 2, BR + n * 16);
      b_l[n] = LDFRAGE(cur, 3, BR + n * 16);
    }
    __builtin_amdgcn_s_barrier();
    __builtin_amdgcn_s_setprio(1);
#pragma unroll
    for (int m = 0; m < 4; ++m)
#pragma unroll
      for (int n = 2; n < 4; ++n) {
        acc[m][n] = MFMA_BF16(a_h[m], b_l[n], acc[m][n], 0, 0, 0);
        acc[m][n] = MFMA_BF16(a_l[m], b_h[n], acc[m][n], 0, 0, 0);
        acc[m][n] = MFMA_BF16(a_h[m], b_h[n], acc[m][n], 0, 0, 0);
      }
    __builtin_amdgcn_s_setprio(0);
    __builtin_amdgcn_s_barrier();  // reads drained before next stage
  }

  const int cr = (lane >> 4) << 2;
  const int cc = lane & 15;
#pragma unroll
  for (int m = 0; m < 4; ++m)
#pragma unroll
    for (int n = 0; n < 4; ++n)
#pragma unroll
      for (int r = 0; r < 4; ++r) {
        const long long row = (long long)by * 128 + wr * 64 + m * 16 + cr + r;
        const long long col = (long long)bx * 128 + wc * 64 + n * 16 + cc;
        attn[(long long)bz * Ss * Ss + row * Ss + col] = acc[m][n][r];
      }
#undef STAGE8E
#undef LDFRAGE
}

// ---------------- 128x128-tile BT-layout MFMA GEMM (NPASS=1) --------------
// EPI: 0 = fp32 store; 2 = bf16 store.  TRIK: truncate K at (by+1)*128.
template <int EPI, bool TRIK>
__global__ __launch_bounds__(256) void k_gemm_bt(
    const u16* __restrict__ Ah, const u16* __restrict__ Bh,
    float* __restrict__ Cf, u16* __restrict__ Ch,
    int M, int N, int K, long long strA, long long strB, long long strC) {
  const int bx = blockIdx.x, by = blockIdx.y, bz = blockIdx.z;

  const int tid = threadIdx.x;
  const int lane = tid & 63;
  const int w = tid >> 6;
  const int wr = w >> 1, wc = w & 1;

  const u16* pAh = Ah + (long long)bz * strA;
  const u16* pBh = Bh + (long long)bz * strB;

  __shared__ __align__(16) u16 lds[2 * 128 * 32];
  char* ldsc = (char*)lds;

  const int srow = tid >> 2;
  const int scol = (tid & 3) * 8;
  const long long arow = (long long)by * 128 + srow;
  const long long brow = (long long)bx * 128 + srow;

  int ktEnd = K / 32;
  if (TRIK) {
    int lim = ((by + 1) * 128) / 32;
    if (lim < ktEnd) ktEnd = lim;
  }

  f32x4 acc[4][4];
#pragma unroll
  for (int i = 0; i < 4; ++i)
#pragma unroll
    for (int j = 0; j < 4; ++j) acc[i][j] = f32x4{0.f, 0.f, 0.f, 0.f};

  for (int kt = 0; kt < ktEnd; ++kt) {
    const int k0 = kt * 32 + scol;
    __syncthreads();
    gload16(pAh + arow * K + k0, ldsc + 0 * 4096 + w * 1024);
    gload16(pAh + (arow + 64) * K + k0, ldsc + 1 * 4096 + w * 1024);
    gload16(pBh + brow * K + k0, ldsc + 8192 + 0 * 4096 + w * 1024);
    gload16(pBh + (brow + 64) * K + k0, ldsc + 8192 + 1 * 4096 + w * 1024);
    __syncthreads();

    const int kk = (lane >> 4) * 8;
    const int ar = wr * 64 + (lane & 15);
    const int br = wc * 64 + (lane & 15);
    bf16x8 avh[4], bvh[4];
#pragma unroll
    for (int m = 0; m < 4; ++m)
      avh[m] = *(const bf16x8*)(lds + (ar + m * 16) * 32 + kk);
#pragma unroll
    for (int n = 0; n < 4; ++n)
      bvh[n] = *(const bf16x8*)(lds + 128 * 32 + (br + n * 16) * 32 + kk);
#pragma unroll
    for (int m = 0; m < 4; ++m)
#pragma unroll
      for (int n = 0; n < 4; ++n)
        acc[m][n] = MFMA_BF16(avh[m], bvh[n], acc[m][n], 0, 0, 0);
  }

  const int cr = wr * 64 + ((lane >> 4) << 2);
  const int cc = wc * 64 + (lane & 15);
  const long long rb = (long long)by * 128 + cr;
  const long long cb = (long long)bx * 128 + cc;
#pragma unroll
  for (int m = 0; m < 4; ++m)
#pragma unroll
    for (int n = 0; n < 4; ++n)
#pragma unroll
      for (int r = 0; r < 4; ++r) {
        const long long idx =
            (long long)bz * strC + (rb + m * 16 + r) * (long long)N + (cb + n * 16);
        const float v = acc[m][n][r];
        if constexpr (EPI == 0) Cf[idx] = v;
        else Ch[idx] = f2bf(v);
      }
}

// ---------------- causal+pad masked row softmax (in-place) ----------------
__global__ __launch_bounds__(256) void k_softmax(float* __restrict__ attn,
                                                 u16* __restrict__ attn_bf,
                                                 const int* __restrict__ mask,
                                                 float inv_scale) {
  const int q = blockIdx.x;
  const int b = blockIdx.y;
  const int tid = threadIdx.x;
  float* row = attn + ((long long)b * Ss + q) * Ss;
  u16* rowb = attn_bf + ((long long)b * Ss + q) * Ss;
  const int* mrow = mask + b * Ss;

  float x[8];
  float m = -3.0e38f;
#pragma unroll
  for (int j = 0; j < 8; ++j) {
    const int k = tid + j * 256;
    const float e = row[k];
    const bool ok = (k <= q) && (mrow[k] != 0);
    const float v = (ok ? e : -1e20f) * inv_scale;
    x[j] = v;
    m = fmaxf(m, v);
  }
#pragma unroll
  for (int o = 32; o > 0; o >>= 1) m = fmaxf(m, __shfl_xor(m, o));
  __shared__ float redm[4], reds[4];
  const int w = tid >> 6;
  if ((tid & 63) == 0) redm[w] = m;
  __syncthreads();
  m = fmaxf(fmaxf(redm[0], redm[1]), fmaxf(redm[2], redm[3]));
  float s = 0.f;
#pragma unroll
  for (int j = 0; j < 8; ++j) {
    x[j] = __expf(x[j] - m);
    s += x[j];
  }
#pragma unroll
  for (int o = 32; o > 0; o >>= 1) s += __shfl_xor(s, o);
  if ((tid & 63) == 0) reds[w] = s;
  __syncthreads();
  s = reds[0] + reds[1] + reds[2] + reds[3];
  const float inv = 1.0f / s;
#pragma unroll
  for (int j = 0; j < 8; ++j) {
    const int k = tid + j * 256;
    const float a = x[j] * inv;
    row[k] = a;
    rowb[k] = f2bf(a);
  }
}

extern "C" void kernel_launch(void* const* d_in, const int* in_sizes, int n_in,
                              void* d_out, int out_size, void* d_ws, size_t ws_size,
                              hipStream_t stream) {
  const float* emb = (const float*)d_in[0];
  const int* mask = (const int*)d_in[1];
  const float* Wq = (const float*)d_in[2];
  const float* Wk = (const float*)d_in[3];
  const float* Wv = (const float*)d_in[4];

  float* out = (float*)d_out;                   // [8,2048,1024] fp32
  float* attn = out + (long long)Bb * Ss * Dd;  // [8,2048,2048] fp32

  char* p = (char*)d_ws;
  u16* emb_hi = (u16*)p;
  u16* emb_lo = emb_hi + (long long)Bb * Ss * Ee;
  u16* attn_bf = emb_hi;  // alias: emb dead before softmax
  u16* q_hi = (u16*)(p + 67108864LL);
  u16* q_lo = q_hi + 16777216LL;
  u16* k_hi = q_lo + 16777216LL;
  u16* k_lo = k_hi + 16777216LL;
  u16* v_t = k_lo + 16777216LL;  // [b][D][S] bf16
  u16* Wq_hi = v_t + 16777216LL;
  u16* Wq_lo = Wq_hi + 1048576LL;
  u16* Wk_hi = Wq_lo + 1048576LL;
  u16* Wk_lo = Wk_hi + 1048576LL;
  u16* Wv_hi = Wk_lo + 1048576LL;

  const float inv_scale = 1.0f / (32.0f + 1.1920929e-07f);

  k_split4<<<16384, 256, 0, stream>>>(emb, emb_hi, emb_lo, (long long)Bb * Ss * Ee / 4);
  k_wt_split<<<dim3(32, 32), 256, 0, stream>>>(Wq, Wq_hi, Wq_lo);
  k_wt_split<<<dim3(32, 32), 256, 0, stream>>>(Wk, Wk_hi, Wk_lo);
  k_wt_split<<<dim3(32, 32), 256, 0, stream>>>(Wv, Wv_hi, nullptr);

  // q/k = emb @ W : M=16384, N=1024, K=1024; flat grid 256 (nbx=4)
  k_gemm256<1><<<256, 512, 0, stream>>>(
      emb_hi, emb_lo, Wq_hi, Wq_lo, nullptr, q_hi, q_lo, 4, 1024, 1024);
  k_gemm256<1><<<256, 512, 0, stream>>>(
      emb_hi, emb_lo, Wk_hi, Wk_lo, nullptr, k_hi, k_lo, 4, 1024, 1024);
  // v^T per batch: [D,S] = Wv^T[D,E] x emb_b (BT), single-pass bf16
  k_gemm_bt<2, false><<<dim3(16, 8, 8), 256, 0, stream>>>(
      Wv_hi, emb_hi, nullptr, v_t,
      1024, 2048, 1024, 0, (long long)Ss * Ee, (long long)Dd * Ss);
  // energy: 128^2 causal tiles, 4-wave 2-blk/CU deep-prefetch
  k_energy128<<<1088, 256, 0, stream>>>(q_hi, q_lo, k_hi, k_lo, attn);
  // softmax rows in-place + bf16 copy
  k_softmax<<<dim3(Ss, Bb), 256, 0, stream>>>(attn, attn_bf, mask, inv_scale);
  // out per batch: [S,D] = attn_bf @ v (v_t is BT operand), K truncated causally
  k_gemm_bt<0, true><<<dim3(8, 16, 8), 256, 0, stream>>>(
      attn_bf, v_t, out, nullptr,
      2048, 1024, 2048, (long long)Ss * Ss, (long long)Dd * Ss, (long long)Ss * Dd);
}